// Round 2
// baseline (68.785 us; speedup 1.0000x reference)
//
#include <hip/hip_runtime.h>

// Sigma = R * diag(exp(s))^2 * R^T per Gaussian.
// Round 1 -> 2: 4 Gaussians/thread, all memory ops as float4 (16B/lane):
//   quats: 4x float4 loads, scales: 3x float4 loads, out: 9x float4 stores.
// Traffic 256 MB total -> ~37 us at the ~7 TB/s this chip's fill achieves.

__device__ __forceinline__ void sigma_from(
    float qw, float qx, float qy, float qz,
    float e0, float e1, float e2,
    float* __restrict__ o)  // writes o[0..8], constant indices after inline
{
    float inv = rsqrtf(qw * qw + qx * qx + qy * qy + qz * qz);
    float w = qw * inv, x = qx * inv, y = qy * inv, z = qz * inv;
    float s0 = __expf(e0), s1 = __expf(e1), s2 = __expf(e2);

    float xx = x * x, yy = y * y, zz = z * z;
    float xy = x * y, xz = x * z, yz = y * z;
    float wx = w * x, wy = w * y, wz = w * z;

    float M00 = (1.f - 2.f * (yy + zz)) * s0, M01 = (2.f * (xy - wz)) * s1, M02 = (2.f * (xz + wy)) * s2;
    float M10 = (2.f * (xy + wz)) * s0, M11 = (1.f - 2.f * (xx + zz)) * s1, M12 = (2.f * (yz - wx)) * s2;
    float M20 = (2.f * (xz - wy)) * s0, M21 = (2.f * (yz + wx)) * s1, M22 = (1.f - 2.f * (xx + yy)) * s2;

    o[0] = M00 * M00 + M01 * M01 + M02 * M02;          // S00
    o[1] = M00 * M10 + M01 * M11 + M02 * M12;          // S01
    o[2] = M00 * M20 + M01 * M21 + M02 * M22;          // S02
    o[3] = o[1];                                       // S10
    o[4] = M10 * M10 + M11 * M11 + M12 * M12;          // S11
    o[5] = M10 * M20 + M11 * M21 + M12 * M22;          // S12
    o[6] = o[2];                                       // S20
    o[7] = o[5];                                       // S21
    o[8] = M20 * M20 + M21 * M21 + M22 * M22;          // S22
}

__global__ __launch_bounds__(256) void gaussian_sigma4_kernel(
    const float4* __restrict__ q4,
    const float4* __restrict__ s4,
    float4* __restrict__ o4,
    int n)
{
    int t = blockIdx.x * blockDim.x + threadIdx.x;
    int base = t * 4;

    if (base + 3 < n) {
        // fast path: 4 Gaussians, fully vectorized
        float4 qa = q4[(size_t)base + 0];
        float4 qb = q4[(size_t)base + 1];
        float4 qc = q4[(size_t)base + 2];
        float4 qd = q4[(size_t)base + 3];
        float4 sA = s4[(size_t)t * 3 + 0];  // s[g0].xyz, s[g1].x
        float4 sB = s4[(size_t)t * 3 + 1];  // s[g1].yz, s[g2].xy
        float4 sC = s4[(size_t)t * 3 + 2];  // s[g2].z, s[g3].xyz

        float o[36];
        sigma_from(qa.x, qa.y, qa.z, qa.w, sA.x, sA.y, sA.z, o + 0);
        sigma_from(qb.x, qb.y, qb.z, qb.w, sA.w, sB.x, sB.y, o + 9);
        sigma_from(qc.x, qc.y, qc.z, qc.w, sB.z, sB.w, sC.x, o + 18);
        sigma_from(qd.x, qd.y, qd.z, qd.w, sC.y, sC.z, sC.w, o + 27);

        float4* dst = o4 + (size_t)t * 9;
        #pragma unroll
        for (int k = 0; k < 9; ++k)
            dst[k] = make_float4(o[4 * k], o[4 * k + 1], o[4 * k + 2], o[4 * k + 3]);
    } else if (base < n) {
        // scalar tail (unused when n % 4 == 0, but correct in general)
        const float* qs = (const float*)q4;
        const float* ss = (const float*)s4;
        float* os = (float*)o4;
        for (int i = base; i < n; ++i) {
            float o[9];
            sigma_from(qs[4 * (size_t)i + 0], qs[4 * (size_t)i + 1],
                       qs[4 * (size_t)i + 2], qs[4 * (size_t)i + 3],
                       ss[3 * (size_t)i + 0], ss[3 * (size_t)i + 1],
                       ss[3 * (size_t)i + 2], o);
            #pragma unroll
            for (int k = 0; k < 9; ++k) os[9 * (size_t)i + k] = o[k];
        }
    }
}

extern "C" void kernel_launch(void* const* d_in, const int* in_sizes, int n_in,
                              void* d_out, int out_size, void* d_ws, size_t ws_size,
                              hipStream_t stream) {
    const float4* quats = (const float4*)d_in[0];
    const float4* scales = (const float4*)d_in[1];
    float4* out = (float4*)d_out;
    int n = in_sizes[0] / 4;  // quats_raw is (N,4)

    int nthreads = (n + 3) / 4;
    int block = 256;
    int grid = (nthreads + block - 1) / block;
    gaussian_sigma4_kernel<<<grid, block, 0, stream>>>(quats, scales, out, n);
}

// Round 4
// 41.689 us; speedup vs baseline: 1.6499x; 1.6499x over previous
//
#include <hip/hip_runtime.h>

// Sigma = R * diag(exp(s))^2 * R^T per Gaussian.
// Round 3 -> 4: same as R3 (LDS-staged fully-coalesced float4 I/O), with the
// nontemporal store done via a native clang ext_vector_type (the builtin
// rejects HIP_vector_type).

#define BLK 256

typedef float f32x4_t __attribute__((ext_vector_type(4)));

__global__ __launch_bounds__(BLK) void gaussian_sigma_lds_kernel(
    const float4* __restrict__ q4,
    const float4* __restrict__ s4,
    float4* __restrict__ o4,
    int n)
{
    __shared__ float lds[BLK * 9];  // 9216 B, reused: scales phase then output phase
    const int tid = threadIdx.x;
    const int gbase = blockIdx.x * BLK;
    const int i = gbase + tid;

    // Phase 1: coalesced scales load into LDS (BLK*3/4 = 192 float4s)
    {
        const int nf4 = (BLK * 3) / 4;                 // 192
        const size_t sbase = (size_t)gbase * 3 / 4;    // gbase*3 divisible by 4 (BLK=256)
        if (tid < nf4) {
            size_t idx = sbase + (size_t)tid;
            if ((idx + 1) * 4 <= (size_t)n * 3) {
                ((float4*)lds)[tid] = s4[idx];
            }
        }
    }
    __syncthreads();

    const bool active = (i < n);
    float e0 = 0.f, e1 = 0.f, e2 = 0.f;
    float4 q = make_float4(1.f, 0.f, 0.f, 0.f);
    if (active) {
        e0 = lds[3 * tid + 0];
        e1 = lds[3 * tid + 1];
        e2 = lds[3 * tid + 2];
        q = q4[i];
    }
    __syncthreads();  // all scale reads done before lds is overwritten

    if (active) {
        float inv = rsqrtf(q.x * q.x + q.y * q.y + q.z * q.z + q.w * q.w);
        float w = q.x * inv, x = q.y * inv, y = q.z * inv, z = q.w * inv;
        float s0 = __expf(e0), s1 = __expf(e1), s2 = __expf(e2);

        float xx = x * x, yy = y * y, zz = z * z;
        float xy = x * y, xz = x * z, yz = y * z;
        float wx = w * x, wy = w * y, wz = w * z;

        float M00 = (1.f - 2.f * (yy + zz)) * s0, M01 = (2.f * (xy - wz)) * s1, M02 = (2.f * (xz + wy)) * s2;
        float M10 = (2.f * (xy + wz)) * s0, M11 = (1.f - 2.f * (xx + zz)) * s1, M12 = (2.f * (yz - wx)) * s2;
        float M20 = (2.f * (xz - wy)) * s0, M21 = (2.f * (yz + wx)) * s1, M22 = (1.f - 2.f * (xx + yy)) * s2;

        float* o = lds + 9 * tid;  // bank stride 9 (odd) -> 2 lanes/bank, free
        float S01 = M00 * M10 + M01 * M11 + M02 * M12;
        float S02 = M00 * M20 + M01 * M21 + M02 * M22;
        float S12 = M10 * M20 + M11 * M21 + M12 * M22;
        o[0] = M00 * M00 + M01 * M01 + M02 * M02;
        o[1] = S01;
        o[2] = S02;
        o[3] = S01;
        o[4] = M10 * M10 + M11 * M11 + M12 * M12;
        o[5] = S12;
        o[6] = S02;
        o[7] = S12;
        o[8] = M20 * M20 + M21 * M21 + M22 * M22;
    }
    __syncthreads();

    // Phase 3: coalesced nontemporal float4 stores (BLK*9/4 = 576 per block)
    {
        const int nf4 = (BLK * 9) / 4;                 // 576
        const size_t obase = (size_t)gbase * 9 / 4;    // gbase*9 divisible by 4
        const f32x4_t* lv = (const f32x4_t*)lds;
        f32x4_t* ov = (f32x4_t*)o4;
        for (int k = tid; k < nf4; k += BLK) {
            size_t idx = obase + (size_t)k;
            if ((idx + 1) * 4 <= (size_t)n * 9) {
                __builtin_nontemporal_store(lv[k], &ov[idx]);
            }
        }
    }
}

extern "C" void kernel_launch(void* const* d_in, const int* in_sizes, int n_in,
                              void* d_out, int out_size, void* d_ws, size_t ws_size,
                              hipStream_t stream) {
    const float4* quats = (const float4*)d_in[0];
    const float4* scales = (const float4*)d_in[1];
    float4* out = (float4*)d_out;
    int n = in_sizes[0] / 4;  // quats_raw is (N,4)

    int grid = (n + BLK - 1) / BLK;
    gaussian_sigma_lds_kernel<<<grid, BLK, 0, stream>>>(quats, scales, out, n);
}